// Round 2
// baseline (121.792 us; speedup 1.0000x reference)
//
#include <hip/hip_runtime.h>
#include <hip/hip_bf16.h>
#include <stdint.h>

// Shapes fixed by the reference: N=8192, F_IN=128, F_OUT=64.
typedef float f32x4 __attribute__((ext_vector_type(4)));
typedef short s16x8 __attribute__((ext_vector_type(8)));
typedef unsigned int u32x4 __attribute__((ext_vector_type(4)));

#define L2E 1.44269504088896f  // log2(e)

__device__ __forceinline__ float bf2f(unsigned short u) {
    return __uint_as_float(((unsigned int)u) << 16);
}
__device__ __forceinline__ unsigned short f2bf_rne(float f) {
    unsigned int u = __float_as_uint(f);
    u += 0x7fffu + ((u >> 16) & 1u);
    return (unsigned short)(u >> 16);
}

// ---------------------------------------------------------------------------
// k_init: zero the atomic accumulators (ws is poisoned 0xAA before each call)
// and, in block 0, detect the input dtype: W interpreted as bf16 is sane
// (|W| <= ~0.6) iff the data really is bf16; f32 data read as ushorts gives
// mantissa-noise exponents >= 0xC0 almost surely among 8192 samples.
// Grid: 520 x 256 (133120 f32x4 stores = 524288 + 8192 floats).
// ---------------------------------------------------------------------------
__global__ __launch_bounds__(256) void k_init(
    const unsigned short* __restrict__ Wu,
    int* __restrict__ flag,
    float* __restrict__ Apart,
    float* __restrict__ rsum)
{
    int gid = blockIdx.x * 256 + threadIdx.x;
    f32x4 z = (f32x4){0.f, 0.f, 0.f, 0.f};
    if (gid < 131072)       *(f32x4*)&Apart[gid * 4] = z;
    else if (gid < 133120)  *(f32x4*)&rsum[(gid - 131072) * 4] = z;

    if (blockIdx.x == 0) {
        __shared__ int any;
        if (threadIdx.x == 0) any = 0;
        __syncthreads();
        int loc = 0;
        for (int i = threadIdx.x; i < 8192; i += 256) {
            unsigned e = (Wu[i] >> 7) & 0xFFu;  // bf16-exponent field of this ushort
            loc |= (e >= 0xC0u);                // |v| >= 2^65 or NaN/Inf -> not bf16 data
        }
        if (loc) atomicOr(&any, 1);
        __syncthreads();
        if (threadIdx.x == 0) flag[0] = any;    // 1 => inputs are f32
    }
}

// ---------------------------------------------------------------------------
// k1: Wh = h@W (MFMA, bf16 internally), f1L=(Wh@a1)*log2e, f2L=(Wh@a2)*log2e,
//     whT[n][i] = bf16(Wh[i][n])  (transposed for k2's B-fragment loads).
// Dual dtype path selected by *flag (wave-uniform branch).
// Grid: 128 x 256; block = 64 rows.
// ---------------------------------------------------------------------------
__global__ __launch_bounds__(256) void k1_wh(
    const void* __restrict__ hv,
    const void* __restrict__ Wv,
    const void* __restrict__ av,
    const int* __restrict__ flag,
    unsigned short* __restrict__ whT,
    float* __restrict__ f1L,
    float* __restrict__ f2L)
{
    __shared__ __align__(16) unsigned short tb[64][72];  // [n][i_local], 144B rows (16B mult)
    const int isF32 = flag[0];
    const unsigned short* hu = (const unsigned short*)hv;
    const float*          hf = (const float*)hv;
    const unsigned short* Wu = (const unsigned short*)Wv;
    const float*          Wf = (const float*)Wv;
    const unsigned short* au = (const unsigned short*)av;
    const float*          af = (const float*)av;

    const int tid  = threadIdx.x;
    const int lane = tid & 63;
    const int w    = tid >> 6;
    const int col  = lane & 15;
    const int quad = lane >> 4;
    const int i0   = blockIdx.x * 64;

    f32x4 D[4];
    #pragma unroll
    for (int f = 0; f < 4; ++f) D[f] = (f32x4){0.f, 0.f, 0.f, 0.f};

    const int rowA = i0 + w * 16 + col;  // A operand: m = lane&15
    #pragma unroll
    for (int cs = 0; cs < 4; ++cs) {     // K = 128 in 4 steps of 32
        s16x8 A;
        if (isF32) {
            f32x4 h0 = *(const f32x4*)&hf[(size_t)rowA * 128 + cs * 32 + quad * 8];
            f32x4 h1 = *(const f32x4*)&hf[(size_t)rowA * 128 + cs * 32 + quad * 8 + 4];
            #pragma unroll
            for (int jj = 0; jj < 4; ++jj) {
                A[jj]     = (short)f2bf_rne(h0[jj]);
                A[4 + jj] = (short)f2bf_rne(h1[jj]);
            }
        } else {
            A = *(const s16x8*)&hu[(size_t)rowA * 128 + cs * 32 + quad * 8];
        }
        #pragma unroll
        for (int f = 0; f < 4; ++f) {    // n0 = f*16; B[k][n]: n=lane&15, k=quad*8+jj
            s16x8 B;
            #pragma unroll
            for (int jj = 0; jj < 8; ++jj) {
                int widx = (cs * 32 + quad * 8 + jj) * 64 + f * 16 + col;
                B[jj] = isF32 ? (short)f2bf_rne(Wf[widx]) : (short)Wu[widx];
            }
            D[f] = __builtin_amdgcn_mfma_f32_16x16x32_bf16(A, B, D[f], 0, 0, 0);
        }
    }

    float a1v[4], a2v[4];
    #pragma unroll
    for (int f = 0; f < 4; ++f) {
        a1v[f] = isF32 ? af[f * 16 + col]      : bf2f(au[f * 16 + col]);
        a2v[f] = isF32 ? af[64 + f * 16 + col] : bf2f(au[64 + f * 16 + col]);
    }

    // D layout: row = quad*4 + r, col-of-Wh = f*16 + (lane&15)
    #pragma unroll
    for (int r = 0; r < 4; ++r) {
        float s1 = D[0][r]*a1v[0] + D[1][r]*a1v[1] + D[2][r]*a1v[2] + D[3][r]*a1v[3];
        float s2 = D[0][r]*a2v[0] + D[1][r]*a2v[1] + D[2][r]*a2v[2] + D[3][r]*a2v[3];
        #pragma unroll
        for (int d = 1; d < 16; d <<= 1) {  // reduce over the 16 cols
            s1 += __shfl_xor(s1, d, 64);
            s2 += __shfl_xor(s2, d, 64);
        }
        if (col == 0) {
            int i = i0 + w * 16 + quad * 4 + r;
            f1L[i] = s1 * L2E;
            f2L[i] = s2 * L2E;
        }
        #pragma unroll
        for (int f = 0; f < 4; ++f)
            tb[f * 16 + col][w * 16 + quad * 4 + r] = f2bf_rne(D[f][r]);
    }
    __syncthreads();
    for (int idx = tid; idx < 512; idx += 256) {  // coalesced transposed write
        int n = idx >> 3, c8 = (idx & 7) << 3;
        *(u32x4*)&whT[(size_t)n * 8192 + i0 + c8] = *(const u32x4*)&tb[n][c8];
    }
}

// ---------------------------------------------------------------------------
// k2: fused attention: for 64 rows x one 1024-j chunk, accumulate
//     Apart[i][n] += sum_j p_ij * Wh[j][n]  and  rsum[i] += sum_j p_ij
// p built in registers directly in MFMA A-fragment layout; denominator via a
// 5th MFMA against an all-ones B fragment (same bf16 p -> ratio errors cancel).
// Grid: (128 row-tiles, 8 j-chunks) x 256 thr.
// ---------------------------------------------------------------------------
__global__ __launch_bounds__(256) void k2_attn(
    const unsigned short* __restrict__ whT,
    const float* __restrict__ f1L,
    const float* __restrict__ f2L,
    float* __restrict__ Apart,
    float* __restrict__ rsum)
{
    __shared__ __align__(16) unsigned short Bt[64][264];  // [n][j_local], 256 + 8 pad
    __shared__ __align__(16) float f2s[256];              // per-stage f2 slice
    const int tid  = threadIdx.x;
    const int lane = tid & 63;
    const int w    = tid >> 6;
    const int col  = lane & 15;
    const int quad = lane >> 4;
    const int i0   = blockIdx.x * 64;
    const int jb   = blockIdx.y * 1024;

    const float f1 = f1L[i0 + w * 16 + col];  // A-fragment row m = lane&15

    f32x4 D0 = (f32x4){0.f,0.f,0.f,0.f}, D1 = D0, D2 = D0, D3 = D0, Ds = D0;
    s16x8 ones;
    #pragma unroll
    for (int jj = 0; jj < 8; ++jj) ones[jj] = (short)0x3f80;  // bf16(1.0)

    for (int s = 0; s < 4; ++s) {            // 4 stages x 256 j
        __syncthreads();
        if (tid < 64)
            *(f32x4*)&f2s[tid * 4] = *(const f32x4*)&f2L[jb + (s << 8) + tid * 4];
        for (int idx = tid; idx < 2048; idx += 256) {  // stage 64 x 256 bf16 tile
            int n = idx >> 5, c = (idx & 31) << 3;
            *(u32x4*)&Bt[n][c] =
                *(const u32x4*)&whT[(size_t)n * 8192 + jb + (s << 8) + c];
        }
        __syncthreads();
        #pragma unroll
        for (int j0 = 0; j0 < 256; j0 += 32) {
            const int jq = j0 + quad * 8;
            f32x4 fa = *(const f32x4*)&f2s[jq];
            f32x4 fb = *(const f32x4*)&f2s[jq + 4];
            unsigned int pb[8];
            #pragma unroll
            for (int e = 0; e < 4; ++e) {
                float u = f1 + fa[e];                       // already *log2e
                u = fmaxf(u, 0.01f * u);                    // LeakyReLU in log2 domain
                u = fminf(fmaxf(u, -126.f), 80.f);          // NaN/Inf insurance
                pb[e] = __float_as_uint(__builtin_amdgcn_exp2f(u));
                float v = f1 + fb[e];
                v = fmaxf(v, 0.01f * v);
                v = fminf(fmaxf(v, -126.f), 80.f);
                pb[4 + e] = __float_as_uint(__builtin_amdgcn_exp2f(v));
            }
            union { u32x4 u4; s16x8 s8; } Au;   // pack truncated bf16 pairs
            Au.u4[0] = __builtin_amdgcn_perm(pb[1], pb[0], 0x07060302u);
            Au.u4[1] = __builtin_amdgcn_perm(pb[3], pb[2], 0x07060302u);
            Au.u4[2] = __builtin_amdgcn_perm(pb[5], pb[4], 0x07060302u);
            Au.u4[3] = __builtin_amdgcn_perm(pb[7], pb[6], 0x07060302u);
            const int jc = j0 + quad * 8;
            s16x8 B0 = *(const s16x8*)&Bt[col][jc];
            s16x8 B1 = *(const s16x8*)&Bt[16 + col][jc];
            s16x8 B2 = *(const s16x8*)&Bt[32 + col][jc];
            s16x8 B3 = *(const s16x8*)&Bt[48 + col][jc];
            D0 = __builtin_amdgcn_mfma_f32_16x16x32_bf16(Au.s8, B0, D0, 0, 0, 0);
            D1 = __builtin_amdgcn_mfma_f32_16x16x32_bf16(Au.s8, B1, D1, 0, 0, 0);
            D2 = __builtin_amdgcn_mfma_f32_16x16x32_bf16(Au.s8, B2, D2, 0, 0, 0);
            D3 = __builtin_amdgcn_mfma_f32_16x16x32_bf16(Au.s8, B3, D3, 0, 0, 0);
            Ds = __builtin_amdgcn_mfma_f32_16x16x32_bf16(Au.s8, ones, Ds, 0, 0, 0);
        }
    }

    #pragma unroll
    for (int r = 0; r < 4; ++r) {   // D layout: row = quad*4+r, col n = 16*b + col
        int i = i0 + w * 16 + quad * 4 + r;
        atomicAdd(&Apart[(size_t)i * 64 +      col], D0[r]);
        atomicAdd(&Apart[(size_t)i * 64 + 16 + col], D1[r]);
        atomicAdd(&Apart[(size_t)i * 64 + 32 + col], D2[r]);
        atomicAdd(&Apart[(size_t)i * 64 + 48 + col], D3[r]);
        if (col == 0) atomicAdd(&rsum[i], Ds[r]);
    }
}

// ---------------------------------------------------------------------------
// k3: out = elu(Apart / rsum), written as bf16 or f32 per detected dtype.
// ---------------------------------------------------------------------------
__global__ __launch_bounds__(256) void k3_combine(
    const float* __restrict__ Apart,
    const float* __restrict__ rsum,
    const int* __restrict__ flag,
    void* __restrict__ outv)
{
    int gid = blockIdx.x * 256 + threadIdx.x;  // 0 .. 524287
    int i = gid >> 6;
    float v = Apart[gid] / rsum[i];
    float r = v > 0.f ? v : (__builtin_amdgcn_exp2f(v * L2E) - 1.f);
    if (flag[0]) ((float*)outv)[gid] = r;
    else         ((unsigned short*)outv)[gid] = f2bf_rne(r);
}

// ---------------------------------------------------------------------------
extern "C" void kernel_launch(void* const* d_in, const int* in_sizes, int n_in,
                              void* d_out, int out_size, void* d_ws, size_t ws_size,
                              hipStream_t stream) {
    const void* h = d_in[0];  // 8192x128
    const void* W = d_in[1];  // 128x64
    const void* a = d_in[2];  // 128x1

    char* ws = (char*)d_ws;
    unsigned short* whT = (unsigned short*)ws;        // 64x8192 bf16 = 1 MB
    float* f1L   = (float*)(ws + 1048576);            // 32 KB
    float* f2L   = (float*)(ws + 1081344);            // 32 KB
    int*   flag  = (int*)  (ws + 1114112);            // 16 B
    float* Apart = (float*)(ws + 1114368);            // 8192x64 f32 = 2 MB
    float* rsum  = (float*)(ws + 3211520);            // 8192 f32 = 32 KB
    // total ws requirement: ~3.25 MB

    k_init<<<520, 256, 0, stream>>>((const unsigned short*)W, flag, Apart, rsum);
    k1_wh<<<128, 256, 0, stream>>>(h, W, a, flag, whT, f1L, f2L);
    k2_attn<<<dim3(128, 8), 256, 0, stream>>>(whT, f1L, f2L, Apart, rsum);
    k3_combine<<<2048, 256, 0, stream>>>(Apart, rsum, flag, d_out);
}